// Round 14
// baseline (159.516 us; speedup 1.0000x reference)
//
#include <hip/hip_runtime.h>
#include <hip/hip_bf16.h>
#include <math.h>

#define SCALE_Q 0.25504522f  // 1/sqrt(32) * log2(e)  (Q pre-scale for exp2 softmax)

typedef unsigned short u16;
typedef unsigned int u32;
typedef __attribute__((ext_vector_type(8))) short bshort8;
typedef __attribute__((ext_vector_type(4))) short sshort4;
typedef __attribute__((ext_vector_type(4))) float f32x4;
typedef __attribute__((ext_vector_type(4))) u32 u32x4;

__device__ inline u16 f2b(float f) {  // fp32 -> bf16 RNE
    union { float f; uint32_t u; } c;
    c.f = f;
    uint32_t u = c.u;
    return (u16)((u + 0x7fffu + ((u >> 16) & 1u)) >> 16);
}

__device__ __forceinline__ float b2f(u16 b) {
    union { u32 u; float f; } c;
    c.u = (u32)b << 16;
    return c.f;
}

__device__ __forceinline__ u32 cvtpk(float a, float b) {  // {lo=bf16(a), hi=bf16(b)}
    u32 r;
    asm("v_cvt_pk_bf16_f32 %0, %1, %2" : "=v"(r) : "v"(a), "v"(b));
    return r;
}

__device__ __forceinline__ float exp2c(float s) {  // 2^min(s,100)
    float c = fminf(s, 100.f);
    float r;
    asm("v_exp_f32 %0, %1" : "=v"(r) : "v"(c));
    return r;
}

__device__ inline void gload_lds16(const void* g, void* lds) {
    __builtin_amdgcn_global_load_lds(
        (const __attribute__((address_space(1))) void*)g,
        (__attribute__((address_space(3))) void*)lds, 16, 0, 0);
}

// ---------------- fp32->bf16 convert helper: 4 elems at flat offset e ----------------
struct WSrc { const float* p[12]; };
__device__ __forceinline__ void conv4(const WSrc& s, u16* __restrict__ dst, long e) {
    int w; long base;
    if (e < 2359296)      { w = (int)(e >> 18); base = (long)w << 18; }
    else if (e < 3407872) { w = 9;  base = 2359296; }
    else if (e < 4456448) { w = 10; base = 3407872; }
    else                  { w = 11; base = 4456448; }
    float4 v = *(const float4*)(s.p[w] + (e - base));
    dst[e + 0] = f2b(v.x); dst[e + 1] = f2b(v.y);
    dst[e + 2] = f2b(v.z); dst[e + 3] = f2b(v.w);
}

// ---------------- prep1: window-reduce + convert {conv_w, sa_qkv, x} ----------------
// blocks [0,256): window |max-min|+eps -> res_tb [b][n][c] bf16 (LDS transpose)
// blocks [256,1280): convert e in [0, 1048576)      (conv_w + sa wq/wk/wv)
// blocks [1280,3328): convert e in [4456448, 6553600)  (x)
__global__ __launch_bounds__(256) void prep1_kernel(WSrc s, u16* __restrict__ dst,
                                                    const float* __restrict__ G,
                                                    u16* __restrict__ Rt) {
    int bid = blockIdx.x;
    if (bid < 256) {
        __shared__ u16 T[64][72];
        int b = bid >> 6, c0 = ((bid >> 3) & 7) << 6, n0 = (bid & 7) << 6;
        int t = threadIdx.x;
        int n = t & 63, cq = t >> 6;
        const float* Gb = G + (long)b * 512 * 4096;
        #pragma unroll
        for (int i = 0; i < 16; i++) {
            int c = i * 4 + cq;
            const float4* p = (const float4*)(Gb + (long)(c0 + c) * 4096 + (n0 + n) * 8);
            float4 a = p[0], bb = p[1];
            float mx = fmaxf(fmaxf(fmaxf(a.x, a.y), fmaxf(a.z, a.w)),
                             fmaxf(fmaxf(bb.x, bb.y), fmaxf(bb.z, bb.w)));
            float mn = fminf(fminf(fminf(a.x, a.y), fminf(a.z, a.w)),
                             fminf(fminf(bb.x, bb.y), fminf(bb.z, bb.w)));
            T[n][c] = f2b(fabsf(mx - mn) + 1e-6f);
        }
        __syncthreads();
        int nr = t >> 2, ck = (t & 3) << 4;
        u16* o = Rt + ((long)(b * 512 + n0 + nr) << 9) + c0 + ck;
        *(bshort8*)o = *(const bshort8*)&T[nr][ck];
        *(bshort8*)(o + 8) = *(const bshort8*)&T[nr][ck + 8];
    } else {
        int i = bid - 256;
        long e = (i < 1024) ? (long)i * 1024 + threadIdx.x * 4
                            : 4456448 + (long)(i - 1024) * 1024 + threadIdx.x * 4;
        conv4(s, dst, e);
    }
}

// ================= GEMM arg bundle =================
struct GArg {
    const u16* A; const u16* Bt;
    const float* bias; const u16* Rres;   // residual read as bf16
    void* Cout;
    int N, K;
    long sA, sB, sC;
    u16* D1; u16* D2;
    const float* bias1; const float* bias2;
    int gx, gy;  // grid decode
};

// ================= shared epilogue =================
template <int BIASMODE, int ACT, bool RESID, int OUTMODE>
__device__ __forceinline__ void gemm_epilogue_elem(
    float v, int row, int col, int N, long zoff,
    const float* bias, const u16* Rres, void* Cout,
    u16* D1, u16* D2, const float* bias1, const float* bias2) {
    if (OUTMODE == 3) {  // fused QKV split
        int grp = col >> 9, c = col & 511;
        float bb = (grp == 0) ? bias[c] : (grp == 1) ? bias1[c] : bias2[c];
        float vv = v + bb;
        if (grp == 0)
            ((u16*)Cout)[(long)row * 512 + c] = f2b(vv * SCALE_Q);
        else if (grp == 1)
            D1[(long)row * 512 + c] = f2b(vv);
        else
            D2[((long)((row >> 10) * 512 + c) << 10) + (row & 1023)] = f2b(vv);
    } else if (OUTMODE == 4) {  // fused KV split
        int grp = col >> 9, c = col & 511;
        float vv = v + ((grp == 0) ? bias[c] : bias1[c]);
        if (grp == 0)
            ((u16*)Cout)[(long)row * 512 + c] = f2b(vv);
        else
            D2[((long)((row >> 9) * 512 + c) << 9) + (row & 511)] = f2b(vv);
    } else {
        if (BIASMODE == 1) v += bias[col];
        if (BIASMODE == 2) v += bias[row];
        if (ACT == 1) v = fmaxf(v, 0.f);
        if (ACT == 2) v = 0.5f * v * (1.f + erff(v * 0.70710678118654752f));
        if (ACT == 3) v *= SCALE_Q;
        if (RESID) v += b2f(Rres[(long)row * N + col]);
        long off = zoff + (long)row * N + col;
        if (OUTMODE == 1) ((u16*)Cout)[off] = f2b(v);
        else              ((float*)Cout)[off] = v;
    }
}

// ---------------- bf16 MFMA GEMM body, 64x64 tile, dbuf counted-vmcnt ----------
// Executed by threads 0-255 (4 waves). 2 barriers per K-tile.
template <int BIASMODE, int ACT, bool RESID, int OUTMODE>
__device__ __forceinline__ void bgemm64_body(
    u16* AsB, u16* BsB, const GArg& ga, int bx, int by, int bz) {
    const u16* A  = ga.A + (long)bz * ga.sA;
    const u16* Bt = ga.Bt + (long)bz * ga.sB;
    int K = ga.K, N = ga.N;
    int tid = threadIdx.x;
    int lane = tid & 63, wv = tid >> 6;
    int wr = wv >> 1, wc = wv & 1;
    int m0 = bx * 64, n0 = by * 64;
    f32x4 acc[2][2] = {};
    int srow = lane >> 3;
    int selem = ((lane & 7) ^ srow) << 3;

    auto STAGE = [&](int buf, int k0) {
        #pragma unroll
        for (int i = 0; i < 2; i++) {
            int roff = i * 32 + wv * 8;
            gload_lds16(A + (long)(m0 + roff + srow) * K + k0 + selem,
                        (char*)(AsB + buf * 4096) + roff * 128);
            gload_lds16(Bt + (long)(n0 + roff + srow) * K + k0 + selem,
                        (char*)(BsB + buf * 4096) + roff * 128);
        }
    };

    int NT = K >> 6;
    STAGE(0, 0);
    int cur = 0;
    for (int kt = 0; kt < NT; ++kt) {
        if (kt + 1 < NT) {
            STAGE(cur ^ 1, (kt + 1) << 6);
            asm volatile("s_waitcnt vmcnt(4)\ns_barrier" ::: "memory");
        } else {
            asm volatile("s_waitcnt vmcnt(0)\ns_barrier" ::: "memory");
        }
        const char* Asc = (const char*)(AsB + cur * 4096);
        const char* Bsc = (const char*)(BsB + cur * 4096);
        #pragma unroll
        for (int ks = 0; ks < 2; ks++) {
            bshort8 af[2], bf[2];
            int kbo = ks * 64 + ((lane >> 4) << 4);
            #pragma unroll
            for (int f = 0; f < 2; f++) {
                int arow = wr * 32 + f * 16 + (lane & 15);
                af[f] = *(const bshort8*)(Asc + arow * 128 + (kbo ^ ((arow & 7) << 4)));
                int brow = wc * 32 + f * 16 + (lane & 15);
                bf[f] = *(const bshort8*)(Bsc + brow * 128 + (kbo ^ ((brow & 7) << 4)));
            }
            #pragma unroll
            for (int fi = 0; fi < 2; fi++)
                #pragma unroll
                for (int fj = 0; fj < 2; fj++)
                    acc[fi][fj] = __builtin_amdgcn_mfma_f32_16x16x32_bf16(
                        af[fi], bf[fj], acc[fi][fj], 0, 0, 0);
        }
        asm volatile("s_barrier" ::: "memory");
        cur ^= 1;
    }
    long zoff = (long)bz * ga.sC;
    #pragma unroll
    for (int fi = 0; fi < 2; fi++)
        #pragma unroll
        for (int fj = 0; fj < 2; fj++)
            #pragma unroll
            for (int r = 0; r < 4; r++) {
                int row = m0 + wr * 32 + fi * 16 + ((lane >> 4) << 2) + r;
                int col = n0 + wc * 32 + fj * 16 + (lane & 15);
                gemm_epilogue_elem<BIASMODE, ACT, RESID, OUTMODE>(
                    acc[fi][fj][r], row, col, N, zoff, ga.bias, ga.Rres, ga.Cout,
                    ga.D1, ga.D2, ga.bias1, ga.bias2);
            }
}

// standalone wrapper (256 threads)
template <int BIASMODE, int ACT, bool RESID, int OUTMODE>
__global__ __launch_bounds__(256) void bgemm64_kernel(GArg ga) {
    __shared__ u16 As[2 * 4096];
    __shared__ u16 Bs[2 * 4096];
    bgemm64_body<BIASMODE, ACT, RESID, OUTMODE>(As, Bs, ga,
        blockIdx.x, blockIdx.y, blockIdx.z);
}

// merged: [0,nblk0) gemm a | [nblk0,nblk1) gemm b | rest: bf16 convert of
// e in [1048576, 4456448) (sa_wo + ca_* + ffn_* weights)
template <int B0, int A0, bool R0, int O0, int B1, int A1, bool R1, int O1>
__global__ __launch_bounds__(256) void pair_conv_kernel(
    GArg a, int nblk0, GArg b, int nblk1, WSrc s, u16* __restrict__ dst) {
    __shared__ u16 As[2 * 4096];
    __shared__ u16 Bs[2 * 4096];
    int bid = blockIdx.x;
    if (bid < nblk0) {
        int xy = a.gx * a.gy;
        int bz = bid / xy, r = bid - bz * xy;
        bgemm64_body<B0, A0, R0, O0>(As, Bs, a, r % a.gx, r / a.gx, bz);
    } else if (bid < nblk1) {
        int bid2 = bid - nblk0;
        int xy = b.gx * b.gy;
        int bz = bid2 / xy, r = bid2 - bz * xy;
        bgemm64_body<B1, A1, R1, O1>(As, Bs, b, r % b.gx, r / b.gx, bz);
    } else {
        long e = 1048576 + (long)(bid - nblk1) * 1024 + threadIdx.x * 4;
        conv4(s, dst, e);
    }
}

// ---------------- fused MFMA flash attention body: 8 waves, triple-buffered ---------
__device__ __forceinline__ void attn_body(
    u16* KsB, u16* VsB,
    const u16* __restrict__ Q, const u16* __restrict__ K,
    const u16* __restrict__ Vt, u16* __restrict__ O, int L, int S,
    int bh, int qy) {
    int b = bh >> 4, h = bh & 15;
    int tid = threadIdx.x;
    int lane = tid & 63, wv = tid >> 6;
    int q0 = qy * 128 + wv * 16;
    int qr = lane & 15, g = lane >> 4, g8 = g * 8;
    int kperm = 8 * (qr >> 2) + (qr & 3);
    int nt = S >> 6;

    const u16* Kb = K + (long)b * S * 512 + h * 32;
    const u16* Vb = Vt + ((long)b * 512 + h * 32) * S;
    bshort8 qf = *(const bshort8*)(Q + ((long)(b * L + q0 + qr)) * 512 + h * 32 + g8);

    const u16* src;
    long step;
    char* d0;
    if (wv < 4) {
        int rk = wv * 16 + (lane >> 2);
        int f = ((rk >> 3) & 3) ^ ((rk >> 1) & 3);
        int sc = (lane & 3) ^ f;
        src = Kb + (long)rk * 512 + sc * 8;
        step = (long)64 * 512;
        d0 = (char*)KsB + wv * 1024;
    } else {
        int rv = (wv - 4) * 8 + (lane >> 3);
        int sc = (lane & 7) ^ (lane >> 3);
        src = Vb + (long)rv * S + sc * 8;
        step = 64;
        d0 = (char*)VsB + (wv - 4) * 1024;
    }

    f32x4 acc0 = {}, acc1 = {}, acc2 = {};
    const bshort8 onesf = { (short)0x3F80, (short)0x3F80, (short)0x3F80, (short)0x3F80,
                            (short)0x3F80, (short)0x3F80, (short)0x3F80, (short)0x3F80 };
    int f0 = (qr >> 2) ^ ((qr >> 1) & 1);
    int f1 = f0 ^ 2;

    gload_lds16(src, d0);
    gload_lds16(src + step, d0 + 4096);
    int cur = 0;
    for (int t = 0; t < nt; ++t) {
        if (t + 2 < nt) {
            int nb = cur + 2; if (nb >= 3) nb -= 3;
            gload_lds16(src + (long)(t + 2) * step, d0 + nb * 4096);
            asm volatile("s_waitcnt vmcnt(2)\ns_barrier" ::: "memory");
        } else if (t + 1 < nt) {
            asm volatile("s_waitcnt vmcnt(1)\ns_barrier" ::: "memory");
        } else {
            asm volatile("s_waitcnt vmcnt(0)\ns_barrier" ::: "memory");
        }
        const char* Kt = (const char*)KsB + cur * 4096;
        const char* Vl = (const char*)VsB + cur * 4096;
        bshort8 a0 = *(const bshort8*)(Kt + kperm * 64 + ((g ^ f0) << 4));
        bshort8 a1 = *(const bshort8*)(Kt + (kperm + 4) * 64 + ((g ^ f1) << 4));
        bshort8 a2 = *(const bshort8*)(Kt + (kperm + 32) * 64 + ((g ^ f0) << 4));
        bshort8 a3 = *(const bshort8*)(Kt + (kperm + 36) * 64 + ((g ^ f1) << 4));
        bshort8 v00 = *(const bshort8*)(Vl + qr * 128 + ((g ^ (qr & 7)) << 4));
        bshort8 v01 = *(const bshort8*)(Vl + qr * 128 + (((g + 4) ^ (qr & 7)) << 4));
        bshort8 v10 = *(const bshort8*)(Vl + (16 + qr) * 128 + ((g ^ (qr & 7)) << 4));
        bshort8 v11 = *(const bshort8*)(Vl + (16 + qr) * 128 + (((g + 4) ^ (qr & 7)) << 4));
        f32x4 zz = {0.f, 0.f, 0.f, 0.f};
        f32x4 st0 = __builtin_amdgcn_mfma_f32_16x16x32_bf16(a0, qf, zz, 0, 0, 0);
        f32x4 st1 = __builtin_amdgcn_mfma_f32_16x16x32_bf16(a1, qf, zz, 0, 0, 0);
        f32x4 st2 = __builtin_amdgcn_mfma_f32_16x16x32_bf16(a2, qf, zz, 0, 0, 0);
        f32x4 st3 = __builtin_amdgcn_mfma_f32_16x16x32_bf16(a3, qf, zz, 0, 0, 0);
        float p0[4], p1[4], p2[4], p3[4];
        #pragma unroll
        for (int r = 0; r < 4; r++) {
            p0[r] = exp2c(st0[r]);
            p1[r] = exp2c(st1[r]);
            p2[r] = exp2c(st2[r]);
            p3[r] = exp2c(st3[r]);
        }
        u32x4 P0 = { cvtpk(p0[0], p0[1]), cvtpk(p0[2], p0[3]),
                     cvtpk(p1[0], p1[1]), cvtpk(p1[2], p1[3]) };
        u32x4 P1 = { cvtpk(p2[0], p2[1]), cvtpk(p2[2], p2[3]),
                     cvtpk(p3[0], p3[1]), cvtpk(p3[2], p3[3]) };
        bshort8 pf0 = *(bshort8*)&P0;
        bshort8 pf1 = *(bshort8*)&P1;
        acc0 = __builtin_amdgcn_mfma_f32_16x16x32_bf16(v00, pf0, acc0, 0, 0, 0);
        acc0 = __builtin_amdgcn_mfma_f32_16x16x32_bf16(v01, pf1, acc0, 0, 0, 0);
        acc1 = __builtin_amdgcn_mfma_f32_16x16x32_bf16(v10, pf0, acc1, 0, 0, 0);
        acc1 = __builtin_amdgcn_mfma_f32_16x16x32_bf16(v11, pf1, acc1, 0, 0, 0);
        acc2 = __builtin_amdgcn_mfma_f32_16x16x32_bf16(onesf, pf0, acc2, 0, 0, 0);
        acc2 = __builtin_amdgcn_mfma_f32_16x16x32_bf16(onesf, pf1, acc2, 0, 0, 0);
        asm volatile("s_barrier" ::: "memory");
        cur = (cur == 2) ? 0 : cur + 1;
    }

    float inv = 1.f / acc2[0];
    u16* op = O + ((long)(b * L + q0 + qr)) * 512 + h * 32 + g * 4;
    sshort4 o0, o1;
    #pragma unroll
    for (int r = 0; r < 4; r++) {
        o0[r] = (short)f2b(acc0[r] * inv);
        o1[r] = (short)f2b(acc1[r] * inv);
    }
    *(sshort4*)op = o0;
    *(sshort4*)(op + 16) = o1;
}

// standalone attention (512 threads)
__global__ __launch_bounds__(512) void attn_mfma_kernel(
    const u16* __restrict__ Q, const u16* __restrict__ K,
    const u16* __restrict__ Vt, u16* __restrict__ O, int L, int S) {
    __shared__ __align__(16) u16 SH[12288];
    attn_body(SH, SH + 6144, Q, K, Vt, O, L, S, blockIdx.x, blockIdx.y);
}

// merged: blocks [0,nAttn) attention | rest: 64x64 GEMM on waves 0-3,
// waves 4-7 execute a barrier-matching accompaniment loop (2 per K-tile).
template <int B1, int A1, bool R1, int O1>
__global__ __launch_bounds__(512) void attn_gemm_kernel(
    const u16* __restrict__ Q, const u16* __restrict__ K,
    const u16* __restrict__ Vt, u16* __restrict__ O, int L, int S,
    int nAttn, GArg g) {
    __shared__ __align__(16) u16 SH[16384];
    int bid = blockIdx.x;
    if (bid < nAttn) {
        attn_body(SH, SH + 6144, Q, K, Vt, O, L, S, bid & 63, bid >> 6);
    } else {
        int bid2 = bid - nAttn;
        if ((threadIdx.x >> 6) < 4) {
            int xy = g.gx * g.gy;
            int bz = bid2 / xy, r = bid2 - bz * xy;
            bgemm64_body<B1, A1, R1, O1>(SH, SH + 8192, g, r % g.gx, r / g.gx, bz);
        } else {
            int NT = g.K >> 6;
            for (int kt = 0; kt < NT; ++kt) {
                __builtin_amdgcn_s_barrier();
                __builtin_amdgcn_s_barrier();
            }
        }
    }
}

// ---------------- layernorm over 512: bf16 in -> bf16 out ----------------
__global__ __launch_bounds__(256) void ln_kernel(const u16* __restrict__ X,
                                                 const float* __restrict__ g,
                                                 const float* __restrict__ bt,
                                                 u16* __restrict__ Yb) {
    int row = blockIdx.x;
    int t = threadIdx.x;
    u32 pack = ((const u32*)(X + (long)row * 512))[t];
    float x0 = b2f((u16)(pack & 0xffff));
    float x1 = b2f((u16)(pack >> 16));
    float s = x0 + x1, ss = x0 * x0 + x1 * x1;
    #pragma unroll
    for (int off = 32; off > 0; off >>= 1) {
        s += __shfl_down(s, off);
        ss += __shfl_down(ss, off);
    }
    __shared__ float sred[4], ssred[4];
    int wid = t >> 6;
    if ((t & 63) == 0) { sred[wid] = s; ssred[wid] = ss; }
    __syncthreads();
    float ts = sred[0] + sred[1] + sred[2] + sred[3];
    float tss = ssred[0] + ssred[1] + ssred[2] + ssred[3];
    float mean = ts * (1.f / 512.f);
    float var = tss * (1.f / 512.f) - mean * mean;
    float rstd = rsqrtf(var + 1e-5f);
    float y0 = (x0 - mean) * rstd * g[2 * t] + bt[2 * t];
    float y1 = (x1 - mean) * rstd * g[2 * t + 1] + bt[2 * t + 1];
    ((u32*)(Yb + (long)row * 512))[t] = cvtpk(y0, y1);
}

// ---------------- LN3 pass 1: per-row mean/rstd from bf16 ----------------
__global__ __launch_bounds__(256) void ln_stats_kernel(const u16* __restrict__ X,
                                                       float2* __restrict__ stats) {
    int row = blockIdx.x * 4 + (threadIdx.x >> 6);
    int lane = threadIdx.x & 63;
    bshort8 v = *(const bshort8*)(X + (long)row * 512 + lane * 8);
    float s = 0.f, ss = 0.f;
    #pragma unroll
    for (int i = 0; i < 8; i++) {
        float f = b2f((u16)v[i]);
        s += f;
        ss += f * f;
    }
    #pragma unroll
    for (int off = 32; off > 0; off >>= 1) {
        s += __shfl_down(s, off);
        ss += __shfl_down(ss, off);
    }
    if (lane == 0) {
        float mean = s * (1.f / 512.f);
        float var = ss * (1.f / 512.f) - mean * mean;
        stats[row] = make_float2(mean, rsqrtf(var + 1e-5f));
    }
}

// ---------------- LN3 pass 2: LDS-tiled transpose + normalize -> [B,512,L] fp32 -----
__global__ __launch_bounds__(256) void ln_trans_kernel(
    const u16* __restrict__ X, const float2* __restrict__ stats,
    const float* __restrict__ g, const float* __restrict__ bt,
    float* __restrict__ Y) {
    __shared__ u16 T[64][66];
    int b = blockIdx.z, l0 = blockIdx.x * 64, c0 = blockIdx.y * 64;
    int t = threadIdx.x;
    int col = t & 63, rq = t >> 6;
    #pragma unroll
    for (int i = 0; i < 16; i++) {
        int row = i * 4 + rq;
        T[row][col] = X[((long)(b * 1024 + l0 + row)) * 512 + c0 + col];
    }
    __syncthreads();
    float2 mr = stats[b * 1024 + l0 + col];
    #pragma unroll
    for (int i = 0; i < 16; i++) {
        int c = i * 4 + rq;
        float val = (b2f(T[col][c]) - mr.x) * mr.y * g[c0 + c] + bt[c0 + c];
        Y[((long)(b * 512 + c0 + c)) * 1024 + l0 + col] = val;
    }
}

extern "C" void kernel_launch(void* const* d_in, const int* in_sizes, int n_in,
                              void* d_out, int out_size, void* d_ws, size_t ws_size,
                              hipStream_t stream) {
    const float* x      = (const float*)d_in[0];
    const float* gfeat  = (const float*)d_in[1];
    const float* conv_w = (const float*)d_in[2];
    const float* conv_b = (const float*)d_in[3];
    const float* sa_wq = (const float*)d_in[4];
    const float* sa_bq = (const float*)d_in[5];
    const float* sa_bk = (const float*)d_in[7];
    const float* sa_bv = (const float*)d_in[9];
    const float* sa_bo = (const float*)d_in[11];
    const float* ca_bq = (const float*)d_in[13];
    const float* ca_bk = (const float*)d_in[15];
    const float* ca_bv = (const float*)d_in[17];
    const float* ca_bo = (const float*)d_in[19];
    const float* ffn_b1 = (const float*)d_in[21];
    const float* ffn_b2 = (const float*)d_in[23];
    const float* n1_g = (const float*)d_in[24];
    const float* n1_b = (const float*)d_in[25];
    const float* n2_g = (const float*)d_in[26];
    const float* n2_b = (const float*)d_in[27];
    const float* n3_g = (const float*)d_in[28];
    const float* n3_b = (const float*)d_in[29];
    (void)ws_size; (void)n_in; (void)in_sizes; (void)out_size;

    const long M_ = 1048576;
    float* W0 = (float*)d_ws;
    u16* hb    = (u16*)W0;           // 2M bf16 (4096x512)
    u16* U = (u16*)(W0 + 4 * M_);
    u16* qb     = U;                 // 2M u16
    u16* kb     = U + 2 * M_;        // 2M
    u16* vtb    = U + 4 * M_;        // 2M   [4][512][1024]
    u16* k2b    = U + 6 * M_;        // 1M
    u16* v2tb   = U + 7 * M_;        // 1M   [4][512][512]
    u16* attb   = U + 8 * M_;        // 2M
    u16* hnb    = U + 10 * M_;       // 2M
    u16* midb   = U + 12 * M_;       // 8M
    u16* wsb    = U + 20 * M_;       // 6.55M
    u16* res_tb = U + 27 * M_;       // 1M (dead after conv; reused as LN3 stats)
    u16* crossb = U + 28 * M_;       // 1M

    float2* ln3_stats = (float2*)res_tb;

    const u16* conv_wb = wsb;
    const u16* sa_wqb = wsb + 262144;   // wq,wk,wv contiguous -> fused QKV weight
    const u16* sa_wob = wsb + 1048576;
    const u16* ca_wqb = wsb + 1310720;
    const u16* ca_wkb = wsb + 1572864;  // wk,wv contiguous -> fused KV weight
    const u16* ca_wob = wsb + 2097152;
    const u16* ffn1b = wsb + 2359296, *ffn2b = wsb + 3407872;
    const u16* xb = wsb + 4456448;

    WSrc ws;
    ws.p[0] = conv_w; ws.p[1] = sa_wq; ws.p[2] = (const float*)d_in[6];
    ws.p[3] = (const float*)d_in[8]; ws.p[4] = (const float*)d_in[10];
    ws.p[5] = (const float*)d_in[12]; ws.p[6] = (const float*)d_in[14];
    ws.p[7] = (const float*)d_in[16]; ws.p[8] = (const float*)d_in[18];
    ws.p[9] = (const float*)d_in[20]; ws.p[10] = (const float*)d_in[22];
    ws.p[11] = x;

    // 1. prep1: window reduce + convert {conv_w, sa_qkv, x}
    prep1_kernel<<<3328, 256, 0, stream>>>(ws, wsb, gfeat, res_tb);

    // 2. MERGED: conv+relu (256) + self QKV proj (1536) + convert rest (3328)
    GArg convA = { conv_wb, res_tb, conv_b, nullptr, crossb, 512, 512,
                   0, 262144, 262144, nullptr, nullptr, nullptr, nullptr, 8, 8 };
    GArg qkvA  = { xb, sa_wqb, sa_bq, nullptr, qb, 1536, 512,
                   0, 0, 0, kb, vtb, sa_bk, sa_bv, 64, 24 };
    pair_conv_kernel<2, 1, false, 1, 1, 0, false, 3><<<5120, 256, 0, stream>>>(
        convA, 256, qkvA, 1792, ws, wsb);

    // 3. MERGED: self attention (512 blk) + cross K2/V2 proj (512 blk)
    GArg kvA = { crossb, ca_wkb, ca_bk, nullptr, k2b, 1024, 512,
                 0, 0, 0, nullptr, v2tb, ca_bv, nullptr, 32, 16 };
    attn_gemm_kernel<1, 0, false, 4><<<1024, 512, 0, stream>>>(
        qb, kb, vtb, attb, 1024, 1024, 512, kvA);

    // 4. out proj + resid xb -> hb bf16
    GArg op1 = { attb, sa_wob, sa_bo, xb, hb, 512, 512,
                 0, 0, 0, nullptr, nullptr, nullptr, nullptr, 64, 8 };
    bgemm64_kernel<1, 0, true, 1><<<dim3(64, 8), 256, 0, stream>>>(op1);

    // 5. LN1 -> hnb bf16
    ln_kernel<<<4096, 256, 0, stream>>>(hb, n1_g, n1_b, hnb);

    // 6. cross Q proj (scaled)
    GArg qA  = { hnb, ca_wqb, ca_bq, nullptr, qb, 512, 512,
                 0, 0, 0, nullptr, nullptr, nullptr, nullptr, 64, 8 };
    bgemm64_kernel<1, 3, false, 1><<<dim3(64, 8), 256, 0, stream>>>(qA);

    // 7. cross attention (S=512) -> attb bf16
    attn_mfma_kernel<<<dim3(64, 8), 512, 0, stream>>>(qb, k2b, v2tb, attb, 1024, 512);

    // 8. out proj + resid hnb -> hb bf16
    GArg op2 = { attb, ca_wob, ca_bo, hnb, hb, 512, 512,
                 0, 0, 0, nullptr, nullptr, nullptr, nullptr, 64, 8 };
    bgemm64_kernel<1, 0, true, 1><<<dim3(64, 8), 256, 0, stream>>>(op2);

    // 9. LN2 -> hnb bf16
    ln_kernel<<<4096, 256, 0, stream>>>(hb, n2_g, n2_b, hnb);

    // 10. FFN up + exact gelu -> midb bf16  [4096,2048]
    GArg f1 = { hnb, ffn1b, ffn_b1, nullptr, midb, 2048, 512,
                0, 0, 0, nullptr, nullptr, nullptr, nullptr, 64, 32 };
    bgemm64_kernel<1, 2, false, 1><<<dim3(64, 32), 256, 0, stream>>>(f1);

    // 11. FFN down + resid hnb -> hb bf16  [4096,512] K=2048
    GArg f2 = { midb, ffn2b, ffn_b2, hnb, hb, 512, 2048,
                0, 0, 0, nullptr, nullptr, nullptr, nullptr, 64, 8 };
    bgemm64_kernel<1, 0, true, 1><<<dim3(64, 8), 256, 0, stream>>>(f2);

    // 12. LN3: per-row stats (bf16 in), then LDS-tiled transpose -> d_out fp32
    ln_stats_kernel<<<1024, 256, 0, stream>>>(hb, ln3_stats);
    ln_trans_kernel<<<dim3(16, 8, 4), 256, 0, stream>>>(
        hb, ln3_stats, n3_g, n3_b, (float*)d_out);
}